// Round 2
// baseline (194.931 us; speedup 1.0000x reference)
//
#include <hip/hip_runtime.h>
#include <stdint.h>

typedef __bf16 bf16;
typedef __bf16 bf16x4 __attribute__((ext_vector_type(4)));
typedef __bf16 bf16x8 __attribute__((ext_vector_type(8)));
typedef float f32x4 __attribute__((ext_vector_type(4)));

#define MFMA16(a, b, c) __builtin_amdgcn_mfma_f32_16x16x32_bf16((a), (b), (c), 0, 0, 0)

#define EMBED 1024
#define SEQ   2048
#define MROWS 4096
// 0.125 * log2(e): Q is pre-scaled so attn can use native v_exp_f32 (exp2).
#define ATTN_QSCALE 0.1803368801111f

__device__ __forceinline__ void gl2lds16(const bf16* g, bf16* l) {
    __builtin_amdgcn_global_load_lds(
        (const __attribute__((address_space(1))) void*)g,
        (__attribute__((address_space(3))) void*)l,
        16, 0, 0);
}

// ---------------------------------------------------------------------------
// fused fp32 -> bf16 cast of x + 4 weight matrices (contiguous dst region)
// ---------------------------------------------------------------------------
__global__ __launch_bounds__(256) void cast_all_kernel(
    const float* __restrict__ x,  const float* __restrict__ Wq,
    const float* __restrict__ Wk, const float* __restrict__ Wv,
    const float* __restrict__ Wo, bf16* __restrict__ dst) {
    const int blk = blockIdx.x;
    const float* src;
    size_t so, dofs;
    if (blk < 2048) {
        src = x; so = (size_t)blk * 2048; dofs = so;
    } else {
        const int w = (blk - 2048) >> 9;
        so  = (size_t)((blk - 2048) & 511) * 2048;
        src = (w == 0) ? Wq : (w == 1) ? Wk : (w == 2) ? Wv : Wo;
        dofs = (size_t)(4 + w) * 1024 * 1024 + so;
    }
    const size_t i = (size_t)threadIdx.x * 8;
    float4 a = *(const float4*)(src + so + i);
    float4 b = *(const float4*)(src + so + i + 4);
    bf16x8 o;
    o[0] = (bf16)a.x; o[1] = (bf16)a.y; o[2] = (bf16)a.z; o[3] = (bf16)a.w;
    o[4] = (bf16)b.x; o[5] = (bf16)b.y; o[6] = (bf16)b.z; o[7] = (bf16)b.w;
    *(bf16x8*)(dst + dofs + i) = o;
}

// ---------------------------------------------------------------------------
// Q/K GEMM path: 128x128 tile, BK=64, 4 waves 2x2, XOR-swizzled LDS.
// ---------------------------------------------------------------------------
template <bool SCALE>
__device__ __forceinline__ void gemm_tile(const bf16* __restrict__ A,
                                          const bf16* __restrict__ W,
                                          const float* __restrict__ bias,
                                          bf16* __restrict__ C,
                                          int m0, int n0, bf16* smem) {
    bf16* As = smem;
    bf16* Bs = smem + 128 * 64;

    const int lane = threadIdx.x & 63;
    const int wv   = threadIdx.x >> 6;
    const int wm   = (wv >> 1) * 64;
    const int wn   = (wv & 1) * 64;
    const int fr   = lane & 15;
    const int quad = lane >> 4;
    const int srow = wv * 8 + (lane >> 3);
    const int swz  = (((lane & 7) ^ ((lane >> 3) & 7))) * 8;

    f32x4 acc[4][4];
#pragma unroll
    for (int mt = 0; mt < 4; ++mt)
#pragma unroll
        for (int nt = 0; nt < 4; ++nt)
            acc[mt][nt] = (f32x4){0.f, 0.f, 0.f, 0.f};

    for (int k0 = 0; k0 < 1024; k0 += 64) {
#pragma unroll
        for (int i = 0; i < 4; ++i) {
            gl2lds16(A + (size_t)(m0 + i * 32 + srow) * 1024 + k0 + swz,
                     &As[(i * 32 + wv * 8) * 64]);
            gl2lds16(W + (size_t)(n0 + i * 32 + srow) * 1024 + k0 + swz,
                     &Bs[(i * 32 + wv * 8) * 64]);
        }
        __syncthreads();
#pragma unroll
        for (int ks = 0; ks < 2; ++ks) {
            const int fcol = ((ks * 4 + quad) ^ (fr & 7)) * 8;
            bf16x8 af[4], bfr[4];
#pragma unroll
            for (int t = 0; t < 4; ++t) {
                af[t]  = *(const bf16x8*)&As[(wm + t * 16 + fr) * 64 + fcol];
                bfr[t] = *(const bf16x8*)&Bs[(wn + t * 16 + fr) * 64 + fcol];
            }
#pragma unroll
            for (int mt = 0; mt < 4; ++mt)
#pragma unroll
                for (int nt = 0; nt < 4; ++nt)
                    acc[mt][nt] = MFMA16(af[mt], bfr[nt], acc[mt][nt]);
        }
        __syncthreads();
    }

    float bv[4];
#pragma unroll
    for (int nt = 0; nt < 4; ++nt)
        bv[nt] = bias[n0 + wn + nt * 16 + fr];
    const int row4 = quad * 4;
#pragma unroll
    for (int mt = 0; mt < 4; ++mt)
#pragma unroll
        for (int nt = 0; nt < 4; ++nt)
#pragma unroll
            for (int r = 0; r < 4; ++r) {
                int m = m0 + wm + mt * 16 + row4 + r;
                int n = n0 + wn + nt * 16 + fr;
                float v = acc[mt][nt][r] + bv[nt];
                if (SCALE) v *= ATTN_QSCALE;
                C[(size_t)m * 1024 + n] = (bf16)v;
            }
}

// ---------------------------------------------------------------------------
// V^T GEMM path: swapped-operand MFMA + LDS round-trip transpose epilogue.
// Token axis of VT is PERMUTED within each 32-token chunk:
//   c' = quad*8 + t'*4 + r   <-  o = t'*16 + quad*4 + r
// so that attn's PV step can consume P^T (from the S^T MFMA C-layout) as a
// full-rate 16x16x32 B-operand without cross-lane data movement.
// ---------------------------------------------------------------------------
__device__ __forceinline__ void v_tile(const bf16* __restrict__ x,
                                       const bf16* __restrict__ Wv,
                                       const float* __restrict__ bias,
                                       bf16* __restrict__ VT,
                                       int m0, int n0, bf16* smem) {
    bf16* As = smem;
    bf16* Bs = smem + 128 * 64;

    const int lane = threadIdx.x & 63;
    const int wv   = threadIdx.x >> 6;
    const int wmW  = (wv >> 1) * 64;
    const int wnT  = (wv & 1) * 64;
    const int f    = lane & 15;
    const int quad = lane >> 4;
    const int srow = wv * 8 + (lane >> 3);
    const int swz  = (((lane & 7) ^ ((lane >> 3) & 7))) * 8;

    f32x4 acc[4][4];
#pragma unroll
    for (int mt = 0; mt < 4; ++mt)
#pragma unroll
        for (int nt = 0; nt < 4; ++nt)
            acc[mt][nt] = (f32x4){0.f, 0.f, 0.f, 0.f};

    for (int k0 = 0; k0 < 1024; k0 += 64) {
#pragma unroll
        for (int i = 0; i < 4; ++i) {
            gl2lds16(x  + (size_t)(m0 + i * 32 + srow) * 1024 + k0 + swz,
                     &As[(i * 32 + wv * 8) * 64]);
            gl2lds16(Wv + (size_t)(n0 + i * 32 + srow) * 1024 + k0 + swz,
                     &Bs[(i * 32 + wv * 8) * 64]);
        }
        __syncthreads();
#pragma unroll
        for (int ks = 0; ks < 2; ++ks) {
            const int fcol = ((ks * 4 + quad) ^ (f & 7)) * 8;
            bf16x8 wf[4], xf[4];
#pragma unroll
            for (int t = 0; t < 4; ++t) {
                wf[t] = *(const bf16x8*)&Bs[(wmW + t * 16 + f) * 64 + fcol];
                xf[t] = *(const bf16x8*)&As[(wnT + t * 16 + f) * 64 + fcol];
            }
#pragma unroll
            for (int mt = 0; mt < 4; ++mt)
#pragma unroll
                for (int nt = 0; nt < 4; ++nt)
                    acc[mt][nt] = MFMA16(wf[mt], xf[nt], acc[mt][nt]);
        }
        __syncthreads();
    }

    float4 b4[4];
#pragma unroll
    for (int mt = 0; mt < 4; ++mt)
        b4[mt] = *(const float4*)&bias[n0 + wmW + mt * 16 + quad * 4];

#pragma unroll
    for (int mt = 0; mt < 4; ++mt)
#pragma unroll
        for (int nt = 0; nt < 4; ++nt) {
            const int tok = wnT + nt * 16 + f;
#pragma unroll
            for (int r = 0; r < 4; ++r) {
                const float bvr = (r == 0) ? b4[mt].x : (r == 1) ? b4[mt].y
                                : (r == 2) ? b4[mt].z : b4[mt].w;
                smem[(wmW + mt * 16 + quad * 4 + r) * 136 + tok] =
                    (bf16)(acc[mt][nt][r] + bvr);
            }
        }
    __syncthreads();

    const int n_r  = threadIdx.x >> 4;
    const int t8   = (threadIdx.x & 15) * 8;       // permuted positions [t8, t8+8)
    const int base = t8 & ~31;                     // 32-token chunk base
    const int u4   = ((t8 >> 3) & 3) * 4;          // quad-group within chunk
    const int bb   = m0 >> 11;
    const int tokg = (m0 & 2047) + t8;
#pragma unroll
    for (int p = 0; p < 8; ++p) {
        const int n_loc = p * 16 + n_r;
        const bf16* row = &smem[n_loc * 136];
        bf16x4 a = *(const bf16x4*)&row[base + u4];         // orig tokens t'=0
        bf16x4 b = *(const bf16x4*)&row[base + 16 + u4];    // orig tokens t'=1
        bf16x8 v = {a[0], a[1], a[2], a[3], b[0], b[1], b[2], b[3]};
        *(bf16x8*)&VT[((size_t)(bb * 1024 + n0 + n_loc)) * 2048 + tokg] = v;
    }
}

// merged Q/K/V projection: 768 blocks -> 3 blocks/CU
__global__ __launch_bounds__(256) void qkv_kernel(
    const bf16* __restrict__ x,
    const bf16* __restrict__ Wq, const float* __restrict__ bq,
    const bf16* __restrict__ Wk, const float* __restrict__ bk,
    const bf16* __restrict__ Wv, const float* __restrict__ bv,
    bf16* __restrict__ Q, bf16* __restrict__ K, bf16* __restrict__ VT) {
    __shared__ __align__(16) bf16 smem[128 * 136];
    const int m0    = blockIdx.x * 128;
    const int which = blockIdx.y >> 3;
    const int n0    = (blockIdx.y & 7) * 128;
    if (which == 0)      gemm_tile<true>(x, Wq, bq, Q, m0, n0, smem);
    else if (which == 1) gemm_tile<false>(x, Wk, bk, K, m0, n0, smem);
    else                 v_tile(x, Wv, bv, VT, m0, n0, smem);
}

// ---------------------------------------------------------------------------
// O-proj GEMM, 128x64 tile, BK=64, 4 waves 2x2, fp32 out.
// ---------------------------------------------------------------------------
__global__ __launch_bounds__(256) void oproj_kernel(
    const bf16* __restrict__ A, const bf16* __restrict__ W,
    const float* __restrict__ bias, float* __restrict__ C) {
    const int m0 = blockIdx.x * 128;
    const int n0 = blockIdx.y * 64;

    __shared__ bf16 As[128 * 64];
    __shared__ bf16 Bs[64 * 64];

    const int lane = threadIdx.x & 63;
    const int wv   = threadIdx.x >> 6;
    const int wm   = (wv >> 1) * 64;
    const int wn   = (wv & 1) * 32;
    const int fr   = lane & 15;
    const int quad = lane >> 4;
    const int srow = wv * 8 + (lane >> 3);
    const int swz  = (((lane & 7) ^ ((lane >> 3) & 7))) * 8;

    f32x4 acc[4][2];
#pragma unroll
    for (int mt = 0; mt < 4; ++mt)
#pragma unroll
        for (int nt = 0; nt < 2; ++nt)
            acc[mt][nt] = (f32x4){0.f, 0.f, 0.f, 0.f};

    for (int k0 = 0; k0 < 1024; k0 += 64) {
#pragma unroll
        for (int i = 0; i < 4; ++i)
            gl2lds16(A + (size_t)(m0 + i * 32 + srow) * 1024 + k0 + swz,
                     &As[(i * 32 + wv * 8) * 64]);
#pragma unroll
        for (int i = 0; i < 2; ++i)
            gl2lds16(W + (size_t)(n0 + i * 32 + srow) * 1024 + k0 + swz,
                     &Bs[(i * 32 + wv * 8) * 64]);
        __syncthreads();
#pragma unroll
        for (int ks = 0; ks < 2; ++ks) {
            const int fcol = ((ks * 4 + quad) ^ (fr & 7)) * 8;
            bf16x8 af[4], bfr[2];
#pragma unroll
            for (int t = 0; t < 4; ++t)
                af[t] = *(const bf16x8*)&As[(wm + t * 16 + fr) * 64 + fcol];
#pragma unroll
            for (int t = 0; t < 2; ++t)
                bfr[t] = *(const bf16x8*)&Bs[(wn + t * 16 + fr) * 64 + fcol];
#pragma unroll
            for (int mt = 0; mt < 4; ++mt)
#pragma unroll
                for (int nt = 0; nt < 2; ++nt)
                    acc[mt][nt] = MFMA16(af[mt], bfr[nt], acc[mt][nt]);
        }
        __syncthreads();
    }

    float bv[2];
#pragma unroll
    for (int nt = 0; nt < 2; ++nt)
        bv[nt] = bias[n0 + wn + nt * 16 + fr];
    const int row4 = quad * 4;
#pragma unroll
    for (int mt = 0; mt < 4; ++mt)
#pragma unroll
        for (int nt = 0; nt < 2; ++nt)
#pragma unroll
            for (int r = 0; r < 4; ++r) {
                int m = m0 + wm + mt * 16 + row4 + r;
                int n = n0 + wn + nt * 16 + fr;
                C[(size_t)m * 1024 + n] = acc[mt][nt][r] + bv[nt];
            }
}

// ---------------------------------------------------------------------------
// Flash attention v10: 256 threads (4 waves), q-tile 128 (32 q/wave, G=2),
// KV range split in 2 (1024 per block, 16 steps of 64) -> 1024 blocks,
// 4 blocks/CU (4 waves/SIMD) for latency hiding.  Q pre-scaled by
// 0.125*log2(e) so softmax uses native v_exp_f32 (exp2).  PV + l-acc on
// full-rate 16x16x32 MFMA via token-permuted VT.  setprio(1) around MFMA
// clusters (role diversity across the 4 resident blocks).
// Writes unnormalized bf16 O-partial + fp32 l-partial; combine finishes.
// ---------------------------------------------------------------------------
__global__ __launch_bounds__(256, 4) void attn_kernel(
    const bf16* __restrict__ Q, const bf16* __restrict__ K,
    const bf16* __restrict__ VT, bf16* __restrict__ Opart,
    float* __restrict__ lpart) {
    const int tid  = threadIdx.x;
    const int lane = tid & 63;
    const int wv   = tid >> 6;       // 0..3
    const int quad = lane >> 4;
    const int f    = lane & 15;
    const int qt   = blockIdx.x >> 1;      // 0..15
    const int half = blockIdx.x & 1;
    const int q0   = qt * 128;
    const int kvb  = half * 1024;
    const int b    = blockIdx.y >> 4;
    const int h    = blockIdx.y & 15;

    const bf16* Qp = Q + ((size_t)b * SEQ) * 1024 + (size_t)h * 64;
    const bf16* Kp = K + ((size_t)b * SEQ) * 1024 + (size_t)h * 64;
    const bf16* Vp = VT + ((size_t)(b * 1024 + h * 64)) * 2048;   // [d][tok']
    bf16*  Op = Opart + (size_t)half * MROWS * 1024
                      + ((size_t)b * SEQ) * 1024 + (size_t)h * 64;
    float* lp = lpart + ((size_t)(half * 2 + b) * 16 + h) * SEQ;

    __shared__ bf16 Ks[2][64 * 64];    // [kv][d], swizzled 16B groups
    __shared__ bf16 VTs[2][64 * 64];   // [d][kv'], swizzled 16B groups

    // Q fragments: wave handles 32 q-rows (2 groups of 16); pre-scaled.
    bf16x8 qf[2][2];
#pragma unroll
    for (int qg = 0; qg < 2; ++qg) {
        const bf16* qrow = Qp + (size_t)(q0 + wv * 32 + qg * 16 + f) * 1024;
        qf[qg][0] = *(const bf16x8*)(qrow + quad * 8);
        qf[qg][1] = *(const bf16x8*)(qrow + 32 + quad * 8);
    }

    const int srow = wv * 8 + (lane >> 3);
    const int swz  = (((lane & 7) ^ ((lane >> 3) & 7))) * 8;
    auto stageK = [&](int kv0, int buf) {
#pragma unroll
        for (int i = 0; i < 2; ++i)
            gl2lds16(Kp + (size_t)(kv0 + i * 32 + srow) * 1024 + swz,
                     &Ks[buf][(i * 32 + wv * 8) * 64]);
    };
    auto stageVT = [&](int kv0, int buf) {
#pragma unroll
        for (int i = 0; i < 2; ++i)
            gl2lds16(Vp + (size_t)(i * 32 + srow) * 2048 + kv0 + swz,
                     &VTs[buf][(i * 32 + wv * 8) * 64]);
    };

    stageK(kvb, 0);
    stageVT(kvb, 0);

    f32x4 oacc[2][4];
#pragma unroll
    for (int qg = 0; qg < 2; ++qg)
#pragma unroll
        for (int t = 0; t < 4; ++t)
            oacc[qg][t] = (f32x4){0.f, 0.f, 0.f, 0.f};
    f32x4 lacc[2];
#pragma unroll
    for (int qg = 0; qg < 2; ++qg)
        lacc[qg] = (f32x4){0.f, 0.f, 0.f, 0.f};
    const bf16x8 ones8 = {(bf16)1.f, (bf16)1.f, (bf16)1.f, (bf16)1.f,
                          (bf16)1.f, (bf16)1.f, (bf16)1.f, (bf16)1.f};
    const f32x4  zero4 = (f32x4){0.f, 0.f, 0.f, 0.f};

    const int fcol0 = (quad ^ (f & 7)) * 8;
    const int fcol1 = ((4 + quad) ^ (f & 7)) * 8;

    __syncthreads();

    auto step = [&](int cur, int nextit) {
        if (nextit < 16) {                 // async prefetch before compute
            stageK(kvb + nextit * 64, cur ^ 1);
            stageVT(kvb + nextit * 64, cur ^ 1);
        }

        // ---- S^T = K Q^T (K-frags read once, reused across q-groups) ----
        bf16x8 kf0[4], kf1[4];
#pragma unroll
        for (int t = 0; t < 4; ++t) {
            kf0[t] = *(const bf16x8*)&Ks[cur][(t * 16 + f) * 64 + fcol0];
            kf1[t] = *(const bf16x8*)&Ks[cur][(t * 16 + f) * 64 + fcol1];
        }
        // P^T packed for 16x16x32: pb8[qg][kt][j] with j<4 from tile 2kt,
        // j>=4 from tile 2kt+1 (matches VT's permuted token order).
        bf16x8 pb8[2][2];
#pragma unroll
        for (int qg = 0; qg < 2; ++qg) {
            f32x4 s[4];
            __builtin_amdgcn_s_setprio(1);
#pragma unroll
            for (int t = 0; t < 4; ++t) {
                s[t] = MFMA16(kf0[t], qf[qg][0], zero4);
                s[t] = MFMA16(kf1[t], qf[qg][1], s[t]);
            }
            __builtin_amdgcn_s_setprio(0);
#pragma unroll
            for (int kt = 0; kt < 2; ++kt) {
#pragma unroll
                for (int r = 0; r < 4; ++r) {
                    pb8[qg][kt][r]     = (bf16)__builtin_amdgcn_exp2f(s[2 * kt][r]);
                    pb8[qg][kt][4 + r] = (bf16)__builtin_amdgcn_exp2f(s[2 * kt + 1][r]);
                }
                lacc[qg] = MFMA16(ones8, pb8[qg][kt], lacc[qg]);
            }
        }

        // ---- O^T += V^T P^T, full-rate 16x16x32 (V-frags reused 2x) ----
        __builtin_amdgcn_s_setprio(1);
#pragma unroll
        for (int dt = 0; dt < 4; ++dt) {
#pragma unroll
            for (int kt = 0; kt < 2; ++kt) {
                const int pc = ((kt * 4 + quad) ^ (f & 7)) * 8;
                bf16x8 vf = *(const bf16x8*)&VTs[cur][(dt * 16 + f) * 64 + pc];
#pragma unroll
                for (int qg = 0; qg < 2; ++qg)
                    oacc[qg][dt] = MFMA16(vf, pb8[qg][kt], oacc[qg][dt]);
            }
        }
        __builtin_amdgcn_s_setprio(0);
        __syncthreads();
    };

    for (int it = 0; it < 16; it += 2) {
        step(0, it + 1);
        step(1, it + 2);
    }

    // ---- store unnormalized O-partial (bf16) + l-partial (fp32) ----
#pragma unroll
    for (int qg = 0; qg < 2; ++qg) {
        const int q = q0 + wv * 32 + qg * 16 + f;
        bf16* orow = Op + (size_t)q * 1024;
#pragma unroll
        for (int dt = 0; dt < 4; ++dt) {
            bf16x4 ov;
#pragma unroll
            for (int r = 0; r < 4; ++r)
                ov[r] = (bf16)oacc[qg][dt][r];
            *(bf16x4*)(orow + dt * 16 + quad * 4) = ov;
        }
        if (quad == 0)
            lp[q] = lacc[qg][0];
    }
}

// ---------------------------------------------------------------------------
// combine: O = (Op1 + Op2) / (l1 + l2), bf16 out.
// ---------------------------------------------------------------------------
__global__ __launch_bounds__(256) void combine_kernel(
    const bf16* __restrict__ Opart, const float* __restrict__ lpart,
    bf16* __restrict__ O) {
    const int gid = blockIdx.x * 256 + threadIdx.x;     // 0..524287
    const int row = gid >> 7;                           // 0..4095
    const int c8  = (gid & 127) * 8;
    const int b   = row >> 11;
    const int tok = row & 2047;
    const int h   = c8 >> 6;

    const float l = lpart[((size_t)(0 * 2 + b) * 16 + h) * SEQ + tok]
                  + lpart[((size_t)(1 * 2 + b) * 16 + h) * SEQ + tok];
    const float inv = 1.0f / l;

    const size_t off = (size_t)row * 1024 + c8;
    bf16x8 a = *(const bf16x8*)&Opart[off];
    bf16x8 c = *(const bf16x8*)&Opart[(size_t)MROWS * 1024 + off];
    bf16x8 o;
#pragma unroll
    for (int i = 0; i < 8; ++i)
        o[i] = (bf16)(((float)a[i] + (float)c[i]) * inv);
    *(bf16x8*)&O[off] = o;
}

extern "C" void kernel_launch(void* const* d_in, const int* in_sizes, int n_in,
                              void* d_out, int out_size, void* d_ws, size_t ws_size,
                              hipStream_t stream) {
    const float* x  = (const float*)d_in[0];
    const float* Wq = (const float*)d_in[1];
    const float* bq = (const float*)d_in[2];
    const float* Wk = (const float*)d_in[3];
    const float* bk = (const float*)d_in[4];
    const float* Wv = (const float*)d_in[5];
    const float* bv = (const float*)d_in[6];
    const float* Wo = (const float*)d_in[7];
    const float* bo = (const float*)d_in[8];
    float* out = (float*)d_out;

    bf16* xb    = (bf16*)d_ws;
    bf16* Wqb   = xb   + (size_t)MROWS * 1024;
    bf16* Wkb   = Wqb  + (size_t)1024 * 1024;
    bf16* Wvb   = Wkb  + (size_t)1024 * 1024;
    bf16* Wob   = Wvb  + (size_t)1024 * 1024;
    bf16* Q     = Wob  + (size_t)1024 * 1024;
    bf16* K     = Q    + (size_t)MROWS * 1024;
    bf16* VT    = K    + (size_t)MROWS * 1024;   // [B*1024 rows][2048 tokens, permuted]
    bf16* O     = VT   + (size_t)MROWS * 1024;
    bf16* Opart = O    + (size_t)MROWS * 1024;   // 2 halves, bf16, 16 MB
    float* lpart = (float*)(Opart + (size_t)2 * MROWS * 1024);  // 512 KB

    cast_all_kernel<<<4096, 256, 0, stream>>>(x, Wq, Wk, Wv, Wo, xb);

    qkv_kernel<<<dim3(32, 24), 256, 0, stream>>>(xb, Wqb, bq, Wkb, bk, Wvb, bv, Q, K, VT);
    attn_kernel<<<dim3(32, 32), 256, 0, stream>>>(Q, K, VT, Opart, lpart);
    combine_kernel<<<2048, 256, 0, stream>>>(Opart, lpart, O);
    oproj_kernel<<<dim3(32, 16), 256, 0, stream>>>(O, Wob, bo, out);
}

// Round 3
// 179.944 us; speedup vs baseline: 1.0833x; 1.0833x over previous
//
#include <hip/hip_runtime.h>
#include <stdint.h>

typedef __bf16 bf16;
typedef __bf16 bf16x4 __attribute__((ext_vector_type(4)));
typedef __bf16 bf16x8 __attribute__((ext_vector_type(8)));
typedef float f32x4 __attribute__((ext_vector_type(4)));

#define MFMA16(a, b, c) __builtin_amdgcn_mfma_f32_16x16x32_bf16((a), (b), (c), 0, 0, 0)

#define EMBED 1024
#define SEQ   2048
#define MROWS 4096
// 0.125 * log2(e): Q is pre-scaled so attn can use native v_exp_f32 (exp2).
#define ATTN_QSCALE 0.1803368801111f

__device__ __forceinline__ void gl2lds16(const bf16* g, bf16* l) {
    __builtin_amdgcn_global_load_lds(
        (const __attribute__((address_space(1))) void*)g,
        (__attribute__((address_space(3))) void*)l,
        16, 0, 0);
}

// ---------------------------------------------------------------------------
// fused fp32 -> bf16 cast of x + 4 weight matrices (contiguous dst region)
// ---------------------------------------------------------------------------
__global__ __launch_bounds__(256) void cast_all_kernel(
    const float* __restrict__ x,  const float* __restrict__ Wq,
    const float* __restrict__ Wk, const float* __restrict__ Wv,
    const float* __restrict__ Wo, bf16* __restrict__ dst) {
    const int blk = blockIdx.x;
    const float* src;
    size_t so, dofs;
    if (blk < 2048) {
        src = x; so = (size_t)blk * 2048; dofs = so;
    } else {
        const int w = (blk - 2048) >> 9;
        so  = (size_t)((blk - 2048) & 511) * 2048;
        src = (w == 0) ? Wq : (w == 1) ? Wk : (w == 2) ? Wv : Wo;
        dofs = (size_t)(4 + w) * 1024 * 1024 + so;
    }
    const size_t i = (size_t)threadIdx.x * 8;
    float4 a = *(const float4*)(src + so + i);
    float4 b = *(const float4*)(src + so + i + 4);
    bf16x8 o;
    o[0] = (bf16)a.x; o[1] = (bf16)a.y; o[2] = (bf16)a.z; o[3] = (bf16)a.w;
    o[4] = (bf16)b.x; o[5] = (bf16)b.y; o[6] = (bf16)b.z; o[7] = (bf16)b.w;
    *(bf16x8*)(dst + dofs + i) = o;
}

// ---------------------------------------------------------------------------
// Q/K GEMM path: 128x128 tile, BK=64, 4 waves 2x2, XOR-swizzled LDS.
// Double-buffered 1-deep pipeline: vmcnt(0) -> s_barrier -> stage(k+1) ->
// compute(k).  Loads for k+1 are in flight during the whole compute of k.
// ---------------------------------------------------------------------------
template <bool SCALE>
__device__ __forceinline__ void gemm_tile(const bf16* __restrict__ A,
                                          const bf16* __restrict__ W,
                                          const float* __restrict__ bias,
                                          bf16* __restrict__ C,
                                          int m0, int n0, bf16* smem) {
    const int lane = threadIdx.x & 63;
    const int wv   = threadIdx.x >> 6;
    const int wm   = (wv >> 1) * 64;
    const int wn   = (wv & 1) * 64;
    const int fr   = lane & 15;
    const int quad = lane >> 4;
    const int srow = wv * 8 + (lane >> 3);
    const int swz  = (((lane & 7) ^ ((lane >> 3) & 7))) * 8;

    f32x4 acc[4][4];
#pragma unroll
    for (int mt = 0; mt < 4; ++mt)
#pragma unroll
        for (int nt = 0; nt < 4; ++nt)
            acc[mt][nt] = (f32x4){0.f, 0.f, 0.f, 0.f};

    auto stage = [&](int kt, int bb) {
        bf16* As = smem + bb * 16384;
        bf16* Bs = As + 8192;
        const int k0 = kt * 64;
#pragma unroll
        for (int i = 0; i < 4; ++i) {
            gl2lds16(A + (size_t)(m0 + i * 32 + srow) * 1024 + k0 + swz,
                     &As[(i * 32 + wv * 8) * 64]);
            gl2lds16(W + (size_t)(n0 + i * 32 + srow) * 1024 + k0 + swz,
                     &Bs[(i * 32 + wv * 8) * 64]);
        }
    };

    stage(0, 0);
#pragma unroll
    for (int kt = 0; kt < 16; ++kt) {
        const int bb = kt & 1;
        asm volatile("s_waitcnt vmcnt(0)" ::: "memory");
        __builtin_amdgcn_s_barrier();
        if (kt < 15) stage(kt + 1, bb ^ 1);
        const bf16* As = smem + bb * 16384;
        const bf16* Bs = As + 8192;
#pragma unroll
        for (int ks = 0; ks < 2; ++ks) {
            const int fcol = ((ks * 4 + quad) ^ (fr & 7)) * 8;
            bf16x8 af[4], bfr[4];
#pragma unroll
            for (int t = 0; t < 4; ++t) {
                af[t]  = *(const bf16x8*)&As[(wm + t * 16 + fr) * 64 + fcol];
                bfr[t] = *(const bf16x8*)&Bs[(wn + t * 16 + fr) * 64 + fcol];
            }
            __builtin_amdgcn_s_setprio(1);
#pragma unroll
            for (int mt = 0; mt < 4; ++mt)
#pragma unroll
                for (int nt = 0; nt < 4; ++nt)
                    acc[mt][nt] = MFMA16(af[mt], bfr[nt], acc[mt][nt]);
            __builtin_amdgcn_s_setprio(0);
        }
    }

    float bv[4];
#pragma unroll
    for (int nt = 0; nt < 4; ++nt)
        bv[nt] = bias[n0 + wn + nt * 16 + fr];
    const int row4 = quad * 4;
#pragma unroll
    for (int mt = 0; mt < 4; ++mt)
#pragma unroll
        for (int nt = 0; nt < 4; ++nt)
#pragma unroll
            for (int r = 0; r < 4; ++r) {
                int m = m0 + wm + mt * 16 + row4 + r;
                int n = n0 + wn + nt * 16 + fr;
                float v = acc[mt][nt][r] + bv[nt];
                if (SCALE) v *= ATTN_QSCALE;
                C[(size_t)m * 1024 + n] = (bf16)v;
            }
}

// ---------------------------------------------------------------------------
// V^T GEMM path: swapped-operand MFMA + LDS round-trip transpose epilogue.
// Token axis of VT is PERMUTED within each 32-token chunk:
//   c' = quad*8 + t'*4 + r   <-  o = t'*16 + quad*4 + r
// Same double-buffered pipeline as gemm_tile.
// ---------------------------------------------------------------------------
__device__ __forceinline__ void v_tile(const bf16* __restrict__ x,
                                       const bf16* __restrict__ Wv,
                                       const float* __restrict__ bias,
                                       bf16* __restrict__ VT,
                                       int m0, int n0, bf16* smem) {
    const int lane = threadIdx.x & 63;
    const int wv   = threadIdx.x >> 6;
    const int wmW  = (wv >> 1) * 64;
    const int wnT  = (wv & 1) * 64;
    const int f    = lane & 15;
    const int quad = lane >> 4;
    const int srow = wv * 8 + (lane >> 3);
    const int swz  = (((lane & 7) ^ ((lane >> 3) & 7))) * 8;

    f32x4 acc[4][4];
#pragma unroll
    for (int mt = 0; mt < 4; ++mt)
#pragma unroll
        for (int nt = 0; nt < 4; ++nt)
            acc[mt][nt] = (f32x4){0.f, 0.f, 0.f, 0.f};

    auto stage = [&](int kt, int bb) {
        bf16* As = smem + bb * 16384;
        bf16* Bs = As + 8192;
        const int k0 = kt * 64;
#pragma unroll
        for (int i = 0; i < 4; ++i) {
            gl2lds16(x  + (size_t)(m0 + i * 32 + srow) * 1024 + k0 + swz,
                     &As[(i * 32 + wv * 8) * 64]);
            gl2lds16(Wv + (size_t)(n0 + i * 32 + srow) * 1024 + k0 + swz,
                     &Bs[(i * 32 + wv * 8) * 64]);
        }
    };

    stage(0, 0);
#pragma unroll
    for (int kt = 0; kt < 16; ++kt) {
        const int bb = kt & 1;
        asm volatile("s_waitcnt vmcnt(0)" ::: "memory");
        __builtin_amdgcn_s_barrier();
        if (kt < 15) stage(kt + 1, bb ^ 1);
        const bf16* As = smem + bb * 16384;
        const bf16* Bs = As + 8192;
#pragma unroll
        for (int ks = 0; ks < 2; ++ks) {
            const int fcol = ((ks * 4 + quad) ^ (f & 7)) * 8;
            bf16x8 wf[4], xf[4];
#pragma unroll
            for (int t = 0; t < 4; ++t) {
                wf[t] = *(const bf16x8*)&Bs[(wmW + t * 16 + f) * 64 + fcol];
                xf[t] = *(const bf16x8*)&As[(wnT + t * 16 + f) * 64 + fcol];
            }
            __builtin_amdgcn_s_setprio(1);
#pragma unroll
            for (int mt = 0; mt < 4; ++mt)
#pragma unroll
                for (int nt = 0; nt < 4; ++nt)
                    acc[mt][nt] = MFMA16(wf[mt], xf[nt], acc[mt][nt]);
            __builtin_amdgcn_s_setprio(0);
        }
    }

    float4 b4[4];
#pragma unroll
    for (int mt = 0; mt < 4; ++mt)
        b4[mt] = *(const float4*)&bias[n0 + wmW + mt * 16 + quad * 4];

    __syncthreads();   // all waves done computing before smem reuse as scratch

#pragma unroll
    for (int mt = 0; mt < 4; ++mt)
#pragma unroll
        for (int nt = 0; nt < 4; ++nt) {
            const int tok = wnT + nt * 16 + f;
#pragma unroll
            for (int r = 0; r < 4; ++r) {
                const float bvr = (r == 0) ? b4[mt].x : (r == 1) ? b4[mt].y
                                : (r == 2) ? b4[mt].z : b4[mt].w;
                smem[(wmW + mt * 16 + quad * 4 + r) * 136 + tok] =
                    (bf16)(acc[mt][nt][r] + bvr);
            }
        }
    __syncthreads();

    const int n_r  = threadIdx.x >> 4;
    const int t8   = (threadIdx.x & 15) * 8;       // permuted positions [t8, t8+8)
    const int base = t8 & ~31;                     // 32-token chunk base
    const int u4   = ((t8 >> 3) & 3) * 4;          // quad-group within chunk
    const int bb   = m0 >> 11;
    const int tokg = (m0 & 2047) + t8;
#pragma unroll
    for (int p = 0; p < 8; ++p) {
        const int n_loc = p * 16 + n_r;
        const bf16* row = &smem[n_loc * 136];
        bf16x4 a = *(const bf16x4*)&row[base + u4];         // orig tokens t'=0
        bf16x4 b = *(const bf16x4*)&row[base + 16 + u4];    // orig tokens t'=1
        bf16x8 v = {a[0], a[1], a[2], a[3], b[0], b[1], b[2], b[3]};
        *(bf16x8*)&VT[((size_t)(bb * 1024 + n0 + n_loc)) * 2048 + tokg] = v;
    }
}

// merged Q/K/V projection
__global__ __launch_bounds__(256) void qkv_kernel(
    const bf16* __restrict__ x,
    const bf16* __restrict__ Wq, const float* __restrict__ bq,
    const bf16* __restrict__ Wk, const float* __restrict__ bk,
    const bf16* __restrict__ Wv, const float* __restrict__ bv,
    bf16* __restrict__ Q, bf16* __restrict__ K, bf16* __restrict__ VT) {
    __shared__ __align__(16) bf16 smem[32768];   // 2 bufs x (As 16KB + Bs 16KB)
    const int m0    = blockIdx.x * 128;
    const int which = blockIdx.y >> 3;
    const int n0    = (blockIdx.y & 7) * 128;
    if (which == 0)      gemm_tile<true>(x, Wq, bq, Q, m0, n0, smem);
    else if (which == 1) gemm_tile<false>(x, Wk, bk, K, m0, n0, smem);
    else                 v_tile(x, Wv, bv, VT, m0, n0, smem);
}

// ---------------------------------------------------------------------------
// O-proj GEMM, 128x64 tile, BK=64, 4 waves 2x2, fp32 out, same pipeline.
// ---------------------------------------------------------------------------
__global__ __launch_bounds__(256) void oproj_kernel(
    const bf16* __restrict__ A, const bf16* __restrict__ W,
    const float* __restrict__ bias, float* __restrict__ C) {
    const int m0 = blockIdx.x * 128;
    const int n0 = blockIdx.y * 64;

    __shared__ __align__(16) bf16 smem[24576];   // 2 bufs x (As 16KB + Bs 8KB)

    const int lane = threadIdx.x & 63;
    const int wv   = threadIdx.x >> 6;
    const int wm   = (wv >> 1) * 64;
    const int wn   = (wv & 1) * 32;
    const int fr   = lane & 15;
    const int quad = lane >> 4;
    const int srow = wv * 8 + (lane >> 3);
    const int swz  = (((lane & 7) ^ ((lane >> 3) & 7))) * 8;

    f32x4 acc[4][2];
#pragma unroll
    for (int mt = 0; mt < 4; ++mt)
#pragma unroll
        for (int nt = 0; nt < 2; ++nt)
            acc[mt][nt] = (f32x4){0.f, 0.f, 0.f, 0.f};

    auto stage = [&](int kt, int bb) {
        bf16* As = smem + bb * 12288;
        bf16* Bs = As + 8192;
        const int k0 = kt * 64;
#pragma unroll
        for (int i = 0; i < 4; ++i)
            gl2lds16(A + (size_t)(m0 + i * 32 + srow) * 1024 + k0 + swz,
                     &As[(i * 32 + wv * 8) * 64]);
#pragma unroll
        for (int i = 0; i < 2; ++i)
            gl2lds16(W + (size_t)(n0 + i * 32 + srow) * 1024 + k0 + swz,
                     &Bs[(i * 32 + wv * 8) * 64]);
    };

    stage(0, 0);
#pragma unroll
    for (int kt = 0; kt < 16; ++kt) {
        const int bb = kt & 1;
        asm volatile("s_waitcnt vmcnt(0)" ::: "memory");
        __builtin_amdgcn_s_barrier();
        if (kt < 15) stage(kt + 1, bb ^ 1);
        const bf16* As = smem + bb * 12288;
        const bf16* Bs = As + 8192;
#pragma unroll
        for (int ks = 0; ks < 2; ++ks) {
            const int fcol = ((ks * 4 + quad) ^ (fr & 7)) * 8;
            bf16x8 af[4], bfr[2];
#pragma unroll
            for (int t = 0; t < 4; ++t)
                af[t] = *(const bf16x8*)&As[(wm + t * 16 + fr) * 64 + fcol];
#pragma unroll
            for (int t = 0; t < 2; ++t)
                bfr[t] = *(const bf16x8*)&Bs[(wn + t * 16 + fr) * 64 + fcol];
            __builtin_amdgcn_s_setprio(1);
#pragma unroll
            for (int mt = 0; mt < 4; ++mt)
#pragma unroll
                for (int nt = 0; nt < 2; ++nt)
                    acc[mt][nt] = MFMA16(af[mt], bfr[nt], acc[mt][nt]);
            __builtin_amdgcn_s_setprio(0);
        }
    }

    float bv[2];
#pragma unroll
    for (int nt = 0; nt < 2; ++nt)
        bv[nt] = bias[n0 + wn + nt * 16 + fr];
    const int row4 = quad * 4;
#pragma unroll
    for (int mt = 0; mt < 4; ++mt)
#pragma unroll
        for (int nt = 0; nt < 2; ++nt)
#pragma unroll
            for (int r = 0; r < 4; ++r) {
                int m = m0 + wm + mt * 16 + row4 + r;
                int n = n0 + wn + nt * 16 + fr;
                C[(size_t)m * 1024 + n] = acc[mt][nt][r] + bv[nt];
            }
}

// ---------------------------------------------------------------------------
// Flash attention v11: 256 threads (4 waves), q-tile 256 (64 q/wave, G=4),
// KV split in 2 (1024/block, 16 steps of 64) -> 512 blocks, 2/CU.
// Ring-4 LDS buffers, 2-deep prefetch with counted vmcnt (never drained to 0
// in steady state): stage(t+2) -> vmcnt(8) -> s_barrier -> compute(t).
// PV + l-acc on full-rate 16x16x32 MFMA via token-permuted VT; exp2 softmax.
// ---------------------------------------------------------------------------
__global__ __launch_bounds__(256, 2) void attn_kernel(
    const bf16* __restrict__ Q, const bf16* __restrict__ K,
    const bf16* __restrict__ VT, bf16* __restrict__ Opart,
    float* __restrict__ lpart) {
    const int tid  = threadIdx.x;
    const int lane = tid & 63;
    const int wv   = tid >> 6;       // 0..3
    const int quad = lane >> 4;
    const int f    = lane & 15;
    const int qt   = blockIdx.x >> 1;      // 0..7
    const int half = blockIdx.x & 1;
    const int q0   = qt * 256;
    const int kvb  = half * 1024;
    const int b    = blockIdx.y >> 4;
    const int h    = blockIdx.y & 15;

    const bf16* Qp = Q + ((size_t)b * SEQ) * 1024 + (size_t)h * 64;
    const bf16* Kp = K + ((size_t)b * SEQ) * 1024 + (size_t)h * 64;
    const bf16* Vp = VT + ((size_t)(b * 1024 + h * 64)) * 2048;   // [d][tok']
    bf16*  Op = Opart + (size_t)half * MROWS * 1024
                      + ((size_t)b * SEQ) * 1024 + (size_t)h * 64;
    float* lp = lpart + ((size_t)(half * 2 + b) * 16 + h) * SEQ;

    __shared__ bf16 Ks[4][64 * 64];    // ring-4 [kv][d], swizzled 16B groups
    __shared__ bf16 VTs[4][64 * 64];   // ring-4 [d][kv'], swizzled 16B groups

    // Q fragments: wave handles 64 q-rows (4 groups of 16); pre-scaled.
    bf16x8 qf[4][2];
#pragma unroll
    for (int qg = 0; qg < 4; ++qg) {
        const bf16* qrow = Qp + (size_t)(q0 + wv * 64 + qg * 16 + f) * 1024;
        qf[qg][0] = *(const bf16x8*)(qrow + quad * 8);
        qf[qg][1] = *(const bf16x8*)(qrow + 32 + quad * 8);
    }

    const int srow = wv * 8 + (lane >> 3);
    const int swz  = (((lane & 7) ^ ((lane >> 3) & 7))) * 8;
    auto stageK = [&](int t, int bb) {
        const int kv0 = kvb + t * 64;
#pragma unroll
        for (int i = 0; i < 2; ++i)
            gl2lds16(Kp + (size_t)(kv0 + i * 32 + srow) * 1024 + swz,
                     &Ks[bb][(i * 32 + wv * 8) * 64]);
    };
    auto stageVT = [&](int t, int bb) {
        const int kv0 = kvb + t * 64;
#pragma unroll
        for (int i = 0; i < 2; ++i)
            gl2lds16(Vp + (size_t)(i * 32 + srow) * 2048 + kv0 + swz,
                     &VTs[bb][(i * 32 + wv * 8) * 64]);
    };

    stageK(0, 0); stageVT(0, 0);
    stageK(1, 1); stageVT(1, 1);

    f32x4 oacc[4][4];
#pragma unroll
    for (int qg = 0; qg < 4; ++qg)
#pragma unroll
        for (int t = 0; t < 4; ++t)
            oacc[qg][t] = (f32x4){0.f, 0.f, 0.f, 0.f};
    f32x4 lacc[4];
#pragma unroll
    for (int qg = 0; qg < 4; ++qg)
        lacc[qg] = (f32x4){0.f, 0.f, 0.f, 0.f};
    const bf16x8 ones8 = {(bf16)1.f, (bf16)1.f, (bf16)1.f, (bf16)1.f,
                          (bf16)1.f, (bf16)1.f, (bf16)1.f, (bf16)1.f};
    const f32x4  zero4 = (f32x4){0.f, 0.f, 0.f, 0.f};

    const int fcol0 = (quad ^ (f & 7)) * 8;
    const int fcol1 = ((4 + quad) ^ (f & 7)) * 8;

    // drain: 8 = steady (stage t+2, keep 2 tiles in flight), 4 = t==14, 0 = t==15
    auto step = [&](int t, int bb, int drain) {
        if (drain == 8) { stageK(t + 2, (t + 2) & 3); stageVT(t + 2, (t + 2) & 3); }
        if (drain == 8)      asm volatile("s_waitcnt vmcnt(8)" ::: "memory");
        else if (drain == 4) asm volatile("s_waitcnt vmcnt(4)" ::: "memory");
        else                 asm volatile("s_waitcnt vmcnt(0)" ::: "memory");
        __builtin_amdgcn_s_barrier();

        // ---- S^T = K Q^T (K-frags read once, reused across 4 q-groups) ----
        bf16x8 kf0[4], kf1[4];
#pragma unroll
        for (int t4 = 0; t4 < 4; ++t4) {
            kf0[t4] = *(const bf16x8*)&Ks[bb][(t4 * 16 + f) * 64 + fcol0];
            kf1[t4] = *(const bf16x8*)&Ks[bb][(t4 * 16 + f) * 64 + fcol1];
        }
        bf16x8 pb8[4][2];
#pragma unroll
        for (int qg = 0; qg < 4; ++qg) {
            f32x4 s[4];
            __builtin_amdgcn_s_setprio(1);
#pragma unroll
            for (int t4 = 0; t4 < 4; ++t4) {
                s[t4] = MFMA16(kf0[t4], qf[qg][0], zero4);
                s[t4] = MFMA16(kf1[t4], qf[qg][1], s[t4]);
            }
            __builtin_amdgcn_s_setprio(0);
#pragma unroll
            for (int kt = 0; kt < 2; ++kt) {
#pragma unroll
                for (int r = 0; r < 4; ++r) {
                    pb8[qg][kt][r]     = (bf16)__builtin_amdgcn_exp2f(s[2 * kt][r]);
                    pb8[qg][kt][4 + r] = (bf16)__builtin_amdgcn_exp2f(s[2 * kt + 1][r]);
                }
                lacc[qg] = MFMA16(ones8, pb8[qg][kt], lacc[qg]);
            }
        }

        // ---- O^T += V^T P^T, full-rate 16x16x32 (V-frags reused 4x) ----
        __builtin_amdgcn_s_setprio(1);
#pragma unroll
        for (int dt = 0; dt < 4; ++dt) {
#pragma unroll
            for (int kt = 0; kt < 2; ++kt) {
                const int pc = ((kt * 4 + quad) ^ (f & 7)) * 8;
                bf16x8 vf = *(const bf16x8*)&VTs[bb][(dt * 16 + f) * 64 + pc];
#pragma unroll
                for (int qg = 0; qg < 4; ++qg)
                    oacc[qg][dt] = MFMA16(vf, pb8[qg][kt], oacc[qg][dt]);
            }
        }
        __builtin_amdgcn_s_setprio(0);
    };

    for (int tt = 0; tt < 12; tt += 4) {
        step(tt, 0, 8); step(tt + 1, 1, 8); step(tt + 2, 2, 8); step(tt + 3, 3, 8);
    }
    step(12, 0, 8); step(13, 1, 8); step(14, 2, 4); step(15, 3, 0);

    // ---- store unnormalized O-partial (bf16) + l-partial (fp32) ----
#pragma unroll
    for (int qg = 0; qg < 4; ++qg) {
        const int q = q0 + wv * 64 + qg * 16 + f;
        bf16* orow = Op + (size_t)q * 1024;
#pragma unroll
        for (int dt = 0; dt < 4; ++dt) {
            bf16x4 ov;
#pragma unroll
            for (int r = 0; r < 4; ++r)
                ov[r] = (bf16)oacc[qg][dt][r];
            *(bf16x4*)(orow + dt * 16 + quad * 4) = ov;
        }
        if (quad == 0)
            lp[q] = lacc[qg][0];
    }
}

// ---------------------------------------------------------------------------
// combine: O = (Op1 + Op2) / (l1 + l2), bf16 out.
// ---------------------------------------------------------------------------
__global__ __launch_bounds__(256) void combine_kernel(
    const bf16* __restrict__ Opart, const float* __restrict__ lpart,
    bf16* __restrict__ O) {
    const int gid = blockIdx.x * 256 + threadIdx.x;     // 0..524287
    const int row = gid >> 7;                           // 0..4095
    const int c8  = (gid & 127) * 8;
    const int b   = row >> 11;
    const int tok = row & 2047;
    const int h   = c8 >> 6;

    const float l = lpart[((size_t)(0 * 2 + b) * 16 + h) * SEQ + tok]
                  + lpart[((size_t)(1 * 2 + b) * 16 + h) * SEQ + tok];
    const float inv = 1.0f / l;

    const size_t off = (size_t)row * 1024 + c8;
    bf16x8 a = *(const bf16x8*)&Opart[off];
    bf16x8 c = *(const bf16x8*)&Opart[(size_t)MROWS * 1024 + off];
    bf16x8 o;
#pragma unroll
    for (int i = 0; i < 8; ++i)
        o[i] = (bf16)(((float)a[i] + (float)c[i]) * inv);
    *(bf16x8*)&O[off] = o;
}

extern "C" void kernel_launch(void* const* d_in, const int* in_sizes, int n_in,
                              void* d_out, int out_size, void* d_ws, size_t ws_size,
                              hipStream_t stream) {
    const float* x  = (const float*)d_in[0];
    const float* Wq = (const float*)d_in[1];
    const float* bq = (const float*)d_in[2];
    const float* Wk = (const float*)d_in[3];
    const float* bk = (const float*)d_in[4];
    const float* Wv = (const float*)d_in[5];
    const float* bv = (const float*)d_in[6];
    const float* Wo = (const float*)d_in[7];
    const float* bo = (const float*)d_in[8];
    float* out = (float*)d_out;

    bf16* xb    = (bf16*)d_ws;
    bf16* Wqb   = xb   + (size_t)MROWS * 1024;
    bf16* Wkb   = Wqb  + (size_t)1024 * 1024;
    bf16* Wvb   = Wkb  + (size_t)1024 * 1024;
    bf16* Wob   = Wvb  + (size_t)1024 * 1024;
    bf16* Q     = Wob  + (size_t)1024 * 1024;
    bf16* K     = Q    + (size_t)MROWS * 1024;
    bf16* VT    = K    + (size_t)MROWS * 1024;   // [B*1024 rows][2048 tokens, permuted]
    bf16* O     = VT   + (size_t)MROWS * 1024;
    bf16* Opart = O    + (size_t)MROWS * 1024;   // 2 halves, bf16, 16 MB
    float* lpart = (float*)(Opart + (size_t)2 * MROWS * 1024);  // 512 KB

    cast_all_kernel<<<4096, 256, 0, stream>>>(x, Wq, Wk, Wv, Wo, xb);

    qkv_kernel<<<dim3(32, 24), 256, 0, stream>>>(xb, Wqb, bq, Wkb, bk, Wvb, bv, Q, K, VT);
    attn_kernel<<<dim3(16, 32), 256, 0, stream>>>(Q, K, VT, Opart, lpart);
    combine_kernel<<<2048, 256, 0, stream>>>(Opart, lpart, O);
    oproj_kernel<<<dim3(32, 16), 256, 0, stream>>>(O, Wob, bo, out);
}